// Round 13
// baseline (85.822 us; speedup 1.0000x reference)
//
#include <hip/hip_runtime.h>
#include <stdint.h>

#define MARGIN 0.3f
#define NROWS 4096
#define DIM   2048
#define ROWB  1024                  // fp4: DIM/2 bytes per row
#define PLANE (NROWS * 16)          // 65536 B: one 16B-column plane
#define KSTEP (4 * PLANE)           // byte stride between K-steps (4 planes)
#define NKS   16
#define BT    128
#define NB    (NROWS / BT)          // 32
#define NBLK  (NB * (NB + 1) / 2)   // 528
#define NBLK4 (NBLK * 4)            // 2112 one-wave blocks (divisible by 8)

typedef float f32x4 __attribute__((ext_vector_type(4)));
typedef int   i32x4 __attribute__((ext_vector_type(4)));
typedef int   i32x8 __attribute__((ext_vector_type(8)));
typedef short s16x8 __attribute__((ext_vector_type(8)));

__device__ __forceinline__ ushort f32_to_bf16(float f) {
  uint32_t u = __float_as_uint(f);
  return (ushort)((u + 0x7FFFu + ((u >> 16) & 1u)) >> 16);
}

// e2m1 quantizer to grid {0,.5,1,1.5,2,3,4,6}, clamp at 6.
__device__ __forceinline__ unsigned f32_to_fp4(float y) {
  unsigned s = (__float_as_uint(y) >> 31) << 3;
  float a = fabsf(y);
  unsigned c;
  if      (a < 0.25f) c = 0;
  else if (a < 0.75f) c = 1;
  else if (a < 1.25f) c = 2;
  else if (a < 1.75f) c = 3;
  else if (a < 2.5f)  c = 4;
  else if (a < 3.5f)  c = 5;
  else if (a < 5.0f)  c = 6;
  else                c = 7;
  return s | c;
}

// ---------------------------------------------------------------------------
// prep16: 16 rows per block (one wave per row). Lane l holds the 32
// CONTIGUOUS elems [32l, 32l+32) of its row -> one 16B plane-chunk after
// quantization. Chunks transpose through a 16KB XOR-swizzled LDS buffer and
// stream out plane-major in 256B-contiguous runs (coalesced).
// Also zeroes the accumulators.
// ---------------------------------------------------------------------------
__global__ __launch_bounds__(1024) void prep16(const float* __restrict__ in,
                                               unsigned char* __restrict__ pn,
                                               float* __restrict__ accum) {
  const int tid  = threadIdx.x;
  const int w    = tid >> 6;          // wave = row_local 0..15
  const int lane = tid & 63;
  const int row  = blockIdx.x * 16 + w;
  if (blockIdx.x == 0 && tid == 0) { accum[0] = 0.f; accum[1] = 0.f; }

  const float4* rp = (const float4*)(in + (size_t)row * DIM);
  float4 v[8];
  #pragma unroll
  for (int i = 0; i < 8; ++i) v[i] = rp[lane * 8 + i];   // 128B contiguous/lane

  float ss = 0.f;
  #pragma unroll
  for (int i = 0; i < 8; ++i)
    ss += v[i].x*v[i].x + v[i].y*v[i].y + v[i].z*v[i].z + v[i].w*v[i].w;
  #pragma unroll
  for (int off = 1; off < 64; off <<= 1) ss += __shfl_xor(ss, off);
  const float sc = 64.0f / fmaxf(sqrtf(ss), 1e-12f);     // norm * 2^6

  union { unsigned char bb[16]; int4 u; } q;
  #pragma unroll
  for (int i = 0; i < 8; ++i) {
    unsigned b0 = f32_to_fp4(v[i].x * sc) | (f32_to_fp4(v[i].y * sc) << 4);
    unsigned b1 = f32_to_fp4(v[i].z * sc) | (f32_to_fp4(v[i].w * sc) << 4);
    q.bb[2*i]   = (unsigned char)b0;
    q.bb[2*i+1] = (unsigned char)b1;
  }

  __shared__ int4 lt[1024];           // [row_local][chunk] with XOR swizzle
  lt[w * 64 + (lane ^ w)] = q.u;
  __syncthreads();

  // write: chunk c = tid: plane p = c>>4, row_local rl = c&15
  const int p = tid >> 4, rl = tid & 15;
  int4 val = lt[rl * 64 + (p ^ rl)];
  *(int4*)(pn + (size_t)p * PLANE + ((size_t)blockIdx.x * 16 + rl) * 16) = val;
}

// ---------------------------------------------------------------------------
// tri_gemm: ONE WAVE PER BLOCK, one 64x64 quadrant of an upper-tri 128x128
// tile (2112 blocks). fp4 e2m1 via mfma_scale_f32_16x16x128_f8f6f4
// (cbsz=blgp=4), scale bytes 0x79 = 2^-6 -> acc = sim directly.
// No LDS/barriers; fragments load straight from the plane-major fp4 matrix.
// __launch_bounds__(64, 2): the grid is TLP-limited (~2 waves/SIMD), so allow
// 256 VGPR/wave -- R12's default cap (68 VGPR) scratched the pipeline and
// serialized every load at full L2 latency (78us). 3-DEEP static pipeline
// (full unroll, %3 indices compile-time): 2-step lead ~= 2x190cy of MFMA
// covers the ~200-400cy L2 latency.
// ---------------------------------------------------------------------------
__device__ __forceinline__ void mm16(const i32x4 (&fa)[4], const i32x4 (&fb)[4],
                                     f32x4 (&acc)[4][4]) {
  const i32x4 z4 = {0, 0, 0, 0};
  i32x8 am[4], bn[4];
  #pragma unroll
  for (int m = 0; m < 4; ++m)
    am[m] = __builtin_shufflevector(fa[m], z4, 0, 1, 2, 3, 4, 5, 6, 7);
  #pragma unroll
  for (int n = 0; n < 4; ++n)
    bn[n] = __builtin_shufflevector(fb[n], z4, 0, 1, 2, 3, 4, 5, 6, 7);
  #pragma unroll
  for (int m = 0; m < 4; ++m)
    #pragma unroll
    for (int n = 0; n < 4; ++n)
      acc[m][n] = __builtin_amdgcn_mfma_scale_f32_16x16x128_f8f6f4(
          am[m], bn[n], acc[m][n],
          4, 4,                      // cbsz=fp4(e2m1), blgp=fp4(e2m1)
          0, 0x79797979,             // scale_a: e8m0 = 2^-6 everywhere
          0, 0x79797979);            // scale_b: e8m0 = 2^-6 everywhere
}

__global__ __launch_bounds__(64, 2) void tri_gemm(const unsigned char* __restrict__ pn,
                                                  float* __restrict__ accum) {
  // XCD-aware bijective swizzle (NBLK4 % 8 == 0); consecutive swz = quadrants
  // of the same tile -> per-XCD L2 locality.
  const int b   = blockIdx.x;
  const int swz = (b & 7) * (NBLK4 / 8) + (b >> 3);
  int t = swz >> 2;
  const int q = swz & 3;
  int bi = 0;
  while (t >= NB - bi) { t -= NB - bi; ++bi; }
  const int bj = bi + t;
  const int wr = q >> 1, wc = q & 1;

  const int lane = threadIdx.x;
  const int fr   = lane & 15;         // fragment row within 16
  const int gq   = lane >> 4;         // 16B k-group within the 64B K-step

  f32x4 acc[4][4] = {};
  const int rowA = bi * BT + wr * 64;
  const int rowB = bj * BT + wc * 64;

  const unsigned char* pA = pn + (size_t)gq * PLANE + (size_t)(rowA + fr) * 16;
  const unsigned char* pB = pn + (size_t)gq * PLANE + (size_t)(rowB + fr) * 16;

  i32x4 fA[3][4], fB[3][4];
  #pragma unroll
  for (int s = 0; s < 2; ++s) {       // prologue: K-steps 0,1
    #pragma unroll
    for (int m = 0; m < 4; ++m) {
      fA[s][m] = *(const i32x4*)(pA + (size_t)s * KSTEP + m * 256);
      fB[s][m] = *(const i32x4*)(pB + (size_t)s * KSTEP + m * 256);
    }
  }

  #pragma unroll
  for (int ks = 0; ks < NKS; ++ks) {  // fully unrolled; %3 indices static
    if (ks + 2 < NKS) {
      #pragma unroll
      for (int m = 0; m < 4; ++m) {
        fA[(ks + 2) % 3][m] = *(const i32x4*)(pA + (size_t)(ks + 2) * KSTEP + m * 256);
        fB[(ks + 2) % 3][m] = *(const i32x4*)(pB + (size_t)(ks + 2) * KSTEP + m * 256);
      }
    }
    mm16(fA[ks % 3], fB[ks % 3], acc);
  }

  // ---- epilogue: mask + wave reduce + 2 atomics (no LDS, 1 wave) ----
  float lsum = 0.f, lcnt = 0.f;
  #pragma unroll
  for (int m = 0; m < 4; ++m) {
    #pragma unroll
    for (int n = 0; n < 4; ++n) {
      #pragma unroll
      for (int r = 0; r < 4; ++r) {
        int gi = rowA + m * 16 + gq * 4 + r;
        int gj = rowB + n * 16 + fr;
        float s = acc[m][n][r];
        if (gi < gj && s > MARGIN) { lsum += s - MARGIN; lcnt += 1.f; }
      }
    }
  }
  #pragma unroll
  for (int off = 32; off; off >>= 1) {
    lsum += __shfl_down(lsum, off);
    lcnt += __shfl_down(lcnt, off);
  }
  if (lane == 0) {
    atomicAdd(&accum[0], lsum);
    atomicAdd(&accum[1], lcnt);
  }
}

// ---------------------------------------------------------------------------
// Fallback (tiny workspace): bf16 on-the-fly convert (verified R2 structure).
// ---------------------------------------------------------------------------
__global__ __launch_bounds__(256) void prep_inv(const float* __restrict__ in,
                                                float* __restrict__ invn,
                                                float* __restrict__ accum) {
  const int row = blockIdx.x;
  const int tid = threadIdx.x;
  if (row == 0 && tid == 0) { accum[0] = 0.f; accum[1] = 0.f; }
  const float4* rp = (const float4*)(in + (size_t)row * DIM);
  float4 v0 = rp[tid * 2];
  float4 v1 = rp[tid * 2 + 1];
  float ss = v0.x*v0.x + v0.y*v0.y + v0.z*v0.z + v0.w*v0.w
           + v1.x*v1.x + v1.y*v1.y + v1.z*v1.z + v1.w*v1.w;
  #pragma unroll
  for (int off = 32; off; off >>= 1) ss += __shfl_down(ss, off);
  __shared__ float wred[4];
  const int lane = tid & 63, w = tid >> 6;
  if (lane == 0) wred[w] = ss;
  __syncthreads();
  if (tid == 0)
    invn[row] = 1.0f / fmaxf(sqrtf(wred[0] + wred[1] + wred[2] + wred[3]), 1e-12f);
}

__global__ __launch_bounds__(256) void tri_gemm_fly(const float* __restrict__ inF,
                                                    const float* __restrict__ invn,
                                                    float* __restrict__ accum) {
  enum { FBK = 64 };
  int t = blockIdx.x, bi = 0;
  while (t >= NB - bi) { t -= NB - bi; ++bi; }
  const int bj = bi + t;

  __shared__ __align__(16) ushort Asm[BT * FBK];
  __shared__ __align__(16) ushort Bsm[BT * FBK];

  const int tid  = threadIdx.x;
  const int lane = tid & 63;
  const int w    = tid >> 6;
  const int wr   = w >> 1, wc = w & 1;

  f32x4 acc[4][4] = {};
  const int rowA = bi * BT, rowB = bj * BT;

  for (int k0 = 0; k0 < DIM; k0 += FBK) {
    if (k0) __syncthreads();
    #pragma unroll
    for (int p = 0; p < 8; ++p) {
      int c   = p * 256 + tid;
      int isB = c >> 10;
      int cc  = c & 1023;
      int r   = cc >> 3;
      int s   = cc & 7;
      const int grow = (isB ? rowB : rowA) + r;
      const float4* src = (const float4*)(inF + (size_t)grow * DIM + k0 + s * 8);
      float4 v0 = src[0], v1 = src[1];
      int4 pack;
      ushort* h = (ushort*)&pack;
      h[0] = f32_to_bf16(v0.x); h[1] = f32_to_bf16(v0.y);
      h[2] = f32_to_bf16(v0.z); h[3] = f32_to_bf16(v0.w);
      h[4] = f32_to_bf16(v1.x); h[5] = f32_to_bf16(v1.y);
      h[6] = f32_to_bf16(v1.z); h[7] = f32_to_bf16(v1.w);
      *(int4*)((isB ? Bsm : Asm) + r * FBK + (s ^ (r & 7)) * 8) = pack;
    }
    __syncthreads();

    s16x8 af[2][4], bfv[2][4];
    const int fr = lane & 15, hi = lane >> 4;
    #pragma unroll
    for (int kk = 0; kk < 2; ++kk)
      #pragma unroll
      for (int m = 0; m < 4; ++m) {
        const int ra = wr * 64 + m * 16 + fr;
        af[kk][m] = *(const s16x8*)(Asm + ra * FBK + ((kk * 4 + hi) ^ (ra & 7)) * 8);
        const int rb = wc * 64 + m * 16 + fr;
        bfv[kk][m] = *(const s16x8*)(Bsm + rb * FBK + ((kk * 4 + hi) ^ (rb & 7)) * 8);
      }
    #pragma unroll
    for (int kk = 0; kk < 2; ++kk)
      #pragma unroll
      for (int m = 0; m < 4; ++m)
        #pragma unroll
        for (int n = 0; n < 4; ++n)
          acc[m][n] = __builtin_amdgcn_mfma_f32_16x16x32_bf16(af[kk][m], bfv[kk][n],
                                                              acc[m][n], 0, 0, 0);
  }

  float lsum = 0.f, lcnt = 0.f;
  const int gib = rowA + wr * 64;
  const int gjb = rowB + wc * 64;
  #pragma unroll
  for (int m = 0; m < 4; ++m)
    #pragma unroll
    for (int n = 0; n < 4; ++n)
      #pragma unroll
      for (int r = 0; r < 4; ++r) {
        int gi = gib + m * 16 + (lane >> 4) * 4 + r;
        int gj = gjb + n * 16 + (lane & 15);
        float s = acc[m][n][r] * invn[gi] * invn[gj];
        if (gi < gj && s > MARGIN) { lsum += s - MARGIN; lcnt += 1.f; }
      }
  #pragma unroll
  for (int off = 32; off; off >>= 1) {
    lsum += __shfl_down(lsum, off);
    lcnt += __shfl_down(lcnt, off);
  }
  __shared__ float rs[4], rc[4];
  if (lane == 0) { rs[w] = lsum; rc[w] = lcnt; }
  __syncthreads();
  if (tid == 0) {
    atomicAdd(&accum[0], rs[0] + rs[1] + rs[2] + rs[3]);
    atomicAdd(&accum[1], rc[0] + rc[1] + rc[2] + rc[3]);
  }
}

__global__ void finalize_kernel(const float* __restrict__ accum, float* __restrict__ out) {
  if (threadIdx.x == 0) out[0] = (accum[1] < 0.5f) ? 0.0f : accum[0] / accum[1];
}

extern "C" void kernel_launch(void* const* d_in, const int* in_sizes, int n_in,
                              void* d_out, int out_size, void* d_ws, size_t ws_size,
                              hipStream_t stream) {
  const float* in = (const float*)d_in[0];
  float* out = (float*)d_out;
  const size_t pn_bytes = (size_t)NROWS * ROWB;   // fp4: 4.2 MB (64 planes)

  if (ws_size >= pn_bytes + 2 * sizeof(float)) {
    unsigned char* pn = (unsigned char*)d_ws;
    float* accum = (float*)((char*)d_ws + pn_bytes);
    prep16<<<NROWS / 16, 1024, 0, stream>>>(in, pn, accum);
    tri_gemm<<<NBLK4, 64, 0, stream>>>(pn, accum);
    finalize_kernel<<<1, 64, 0, stream>>>(accum, out);
  } else {
    float* invn  = (float*)d_ws;
    float* accum = (float*)((char*)d_ws + NROWS * sizeof(float));
    prep_inv<<<NROWS, 256, 0, stream>>>(in, invn, accum);
    tri_gemm_fly<<<NBLK, 256, 0, stream>>>(in, invn, accum);
    finalize_kernel<<<1, 64, 0, stream>>>(accum, out);
  }
}

// Round 14
// 82.322 us; speedup vs baseline: 1.0425x; 1.0425x over previous
//
#include <hip/hip_runtime.h>
#include <stdint.h>

#define MARGIN 0.3f
#define NROWS 4096
#define DIM   2048
#define ROWB  1024                  // fp4: DIM/2 bytes per row
#define PLANE (NROWS * 16)          // 65536 B: one 16B-column plane
#define KSTEP (4 * PLANE)           // byte stride between K-steps (4 planes)
#define NKS   16
#define BT    128
#define NB    (NROWS / BT)          // 32
#define NBLK  (NB * (NB + 1) / 2)   // 528
#define NBLK4 (NBLK * 4)            // 2112 one-wave blocks (divisible by 8)

typedef float f32x4 __attribute__((ext_vector_type(4)));
typedef int   i32x4 __attribute__((ext_vector_type(4)));
typedef int   i32x8 __attribute__((ext_vector_type(8)));
typedef short s16x8 __attribute__((ext_vector_type(8)));

__device__ __forceinline__ ushort f32_to_bf16(float f) {
  uint32_t u = __float_as_uint(f);
  return (ushort)((u + 0x7FFFu + ((u >> 16) & 1u)) >> 16);
}

// e2m1 quantizer to grid {0,.5,1,1.5,2,3,4,6}, clamp at 6.
__device__ __forceinline__ unsigned f32_to_fp4(float y) {
  unsigned s = (__float_as_uint(y) >> 31) << 3;
  float a = fabsf(y);
  unsigned c;
  if      (a < 0.25f) c = 0;
  else if (a < 0.75f) c = 1;
  else if (a < 1.25f) c = 2;
  else if (a < 1.75f) c = 3;
  else if (a < 2.5f)  c = 4;
  else if (a < 3.5f)  c = 5;
  else if (a < 5.0f)  c = 6;
  else                c = 7;
  return s | c;
}

// ---------------------------------------------------------------------------
// prep16: 16 rows per block (one wave per row). Lane l holds the 32
// CONTIGUOUS elems of its row -> one 16B plane-chunk after quantization.
// Chunks transpose through a 16KB XOR-swizzled LDS buffer and stream out
// plane-major in 256B-contiguous runs (coalesced). Zeroes the accumulators.
// ---------------------------------------------------------------------------
__global__ __launch_bounds__(1024) void prep16(const float* __restrict__ in,
                                               unsigned char* __restrict__ pn,
                                               float* __restrict__ accum) {
  const int tid  = threadIdx.x;
  const int w    = tid >> 6;          // wave = row_local 0..15
  const int lane = tid & 63;
  const int row  = blockIdx.x * 16 + w;
  if (blockIdx.x == 0 && tid == 0) { accum[0] = 0.f; accum[1] = 0.f; }

  const float4* rp = (const float4*)(in + (size_t)row * DIM);
  float4 v[8];
  #pragma unroll
  for (int i = 0; i < 8; ++i) v[i] = rp[lane * 8 + i];   // 128B contiguous/lane

  float ss = 0.f;
  #pragma unroll
  for (int i = 0; i < 8; ++i)
    ss += v[i].x*v[i].x + v[i].y*v[i].y + v[i].z*v[i].z + v[i].w*v[i].w;
  #pragma unroll
  for (int off = 1; off < 64; off <<= 1) ss += __shfl_xor(ss, off);
  const float sc = 64.0f / fmaxf(sqrtf(ss), 1e-12f);     // norm * 2^6

  union { unsigned char bb[16]; int4 u; } q;
  #pragma unroll
  for (int i = 0; i < 8; ++i) {
    unsigned b0 = f32_to_fp4(v[i].x * sc) | (f32_to_fp4(v[i].y * sc) << 4);
    unsigned b1 = f32_to_fp4(v[i].z * sc) | (f32_to_fp4(v[i].w * sc) << 4);
    q.bb[2*i]   = (unsigned char)b0;
    q.bb[2*i+1] = (unsigned char)b1;
  }

  __shared__ int4 lt[1024];           // [row_local][chunk] with XOR swizzle
  lt[w * 64 + (lane ^ w)] = q.u;
  __syncthreads();

  const int p = tid >> 4, rl = tid & 15;
  int4 val = lt[rl * 64 + (p ^ rl)];
  *(int4*)(pn + (size_t)p * PLANE + ((size_t)blockIdx.x * 16 + rl) * 16) = val;
}

// ---------------------------------------------------------------------------
// tri_gemm: ONE WAVE PER BLOCK, one 64x64 quadrant of an upper-tri 128x128
// tile (2112 blocks). fp4 e2m1 via mfma_scale_f32_16x16x128_f8f6f4
// (cbsz=blgp=4), scale 0x79 = 2^-6 -> acc = sim directly.
// No LDS/barriers. R13 lesson: intrinsic loads get SUNK to uses by the
// scheduler (VGPR stayed 72, every load serialized at ~700cy). This version
// forces a 3-deep pipeline with INLINE-ASM global_load_dwordx4 (asm outputs
// must stay live; asm-volatile order pins issue-early) + counted
// s_waitcnt vmcnt(16) + sched_barrier(0) (rule #18: register-only MFMA
// otherwise hoists past an asm waitcnt).
// ---------------------------------------------------------------------------
#define GLD(dst, addr, OFF) \
  asm volatile("global_load_dwordx4 %0, %1, off offset:" OFF \
               : "=v"(dst) : "v"(addr))

#define GLD8(s, aA, aB) \
  GLD(fA[s][0], aA, "0");   GLD(fA[s][1], aA, "256"); \
  GLD(fA[s][2], aA, "512"); GLD(fA[s][3], aA, "768"); \
  GLD(fB[s][0], aB, "0");   GLD(fB[s][1], aB, "256"); \
  GLD(fB[s][2], aB, "512"); GLD(fB[s][3], aB, "768")

__device__ __forceinline__ void mm16(const i32x4 (&fa)[4], const i32x4 (&fb)[4],
                                     f32x4 (&acc)[4][4]) {
  const i32x4 z4 = {0, 0, 0, 0};
  i32x8 am[4], bn[4];
  #pragma unroll
  for (int m = 0; m < 4; ++m)
    am[m] = __builtin_shufflevector(fa[m], z4, 0, 1, 2, 3, 4, 5, 6, 7);
  #pragma unroll
  for (int n = 0; n < 4; ++n)
    bn[n] = __builtin_shufflevector(fb[n], z4, 0, 1, 2, 3, 4, 5, 6, 7);
  #pragma unroll
  for (int m = 0; m < 4; ++m)
    #pragma unroll
    for (int n = 0; n < 4; ++n)
      acc[m][n] = __builtin_amdgcn_mfma_scale_f32_16x16x128_f8f6f4(
          am[m], bn[n], acc[m][n],
          4, 4,                      // cbsz=fp4(e2m1), blgp=fp4(e2m1)
          0, 0x79797979,             // scale_a: e8m0 = 2^-6 everywhere
          0, 0x79797979);            // scale_b: e8m0 = 2^-6 everywhere
}

__global__ __launch_bounds__(64, 2) void tri_gemm(const unsigned char* __restrict__ pn,
                                                  float* __restrict__ accum) {
  // XCD-aware bijective swizzle (NBLK4 % 8 == 0); consecutive swz = quadrants
  // of the same tile -> per-XCD L2 locality.
  const int b   = blockIdx.x;
  const int swz = (b & 7) * (NBLK4 / 8) + (b >> 3);
  int t = swz >> 2;
  const int q = swz & 3;
  int bi = 0;
  while (t >= NB - bi) { t -= NB - bi; ++bi; }
  const int bj = bi + t;
  const int wr = q >> 1, wc = q & 1;

  const int lane = threadIdx.x;
  const int fr   = lane & 15;         // fragment row within 16
  const int gq   = lane >> 4;         // 16B k-group within the 64B K-step

  f32x4 acc[4][4] = {};
  const int rowA = bi * BT + wr * 64;
  const int rowB = bj * BT + wc * 64;

  uint64_t aA = (uint64_t)(pn + (size_t)gq * PLANE + (size_t)(rowA + fr) * 16);
  uint64_t aB = (uint64_t)(pn + (size_t)gq * PLANE + (size_t)(rowB + fr) * 16);

  i32x4 fA[3][4], fB[3][4];

  // prologue: issue K-steps 0,1 (16 loads)
  GLD8(0, aA, aB); aA += KSTEP; aB += KSTEP;
  GLD8(1, aA, aB); aA += KSTEP; aB += KSTEP;

  #pragma unroll
  for (int ks = 0; ks < NKS; ++ks) {  // fully unrolled; all indices static
    if (ks + 2 < NKS) {
      const int s = (ks + 2) % 3;
      GLD8(s, aA, aB); aA += KSTEP; aB += KSTEP;
    }
    const int rem = 8 * (NKS - 1 - ks);       // loads not yet needed
    if (rem >= 16)      { asm volatile("s_waitcnt vmcnt(16)" ::: "memory"); }
    else if (rem == 8)  { asm volatile("s_waitcnt vmcnt(8)"  ::: "memory"); }
    else                { asm volatile("s_waitcnt vmcnt(0)"  ::: "memory"); }
    __builtin_amdgcn_sched_barrier(0);
    mm16(fA[ks % 3], fB[ks % 3], acc);
  }

  // ---- epilogue: mask + wave reduce + 2 atomics (no LDS, 1 wave) ----
  float lsum = 0.f, lcnt = 0.f;
  #pragma unroll
  for (int m = 0; m < 4; ++m) {
    #pragma unroll
    for (int n = 0; n < 4; ++n) {
      #pragma unroll
      for (int r = 0; r < 4; ++r) {
        int gi = rowA + m * 16 + gq * 4 + r;
        int gj = rowB + n * 16 + fr;
        float s = acc[m][n][r];
        if (gi < gj && s > MARGIN) { lsum += s - MARGIN; lcnt += 1.f; }
      }
    }
  }
  #pragma unroll
  for (int off = 32; off; off >>= 1) {
    lsum += __shfl_down(lsum, off);
    lcnt += __shfl_down(lcnt, off);
  }
  if (lane == 0) {
    atomicAdd(&accum[0], lsum);
    atomicAdd(&accum[1], lcnt);
  }
}

// ---------------------------------------------------------------------------
// Fallback (tiny workspace): bf16 on-the-fly convert (verified R2 structure).
// ---------------------------------------------------------------------------
__global__ __launch_bounds__(256) void prep_inv(const float* __restrict__ in,
                                                float* __restrict__ invn,
                                                float* __restrict__ accum) {
  const int row = blockIdx.x;
  const int tid = threadIdx.x;
  if (row == 0 && tid == 0) { accum[0] = 0.f; accum[1] = 0.f; }
  const float4* rp = (const float4*)(in + (size_t)row * DIM);
  float4 v0 = rp[tid * 2];
  float4 v1 = rp[tid * 2 + 1];
  float ss = v0.x*v0.x + v0.y*v0.y + v0.z*v0.z + v0.w*v0.w
           + v1.x*v1.x + v1.y*v1.y + v1.z*v1.z + v1.w*v1.w;
  #pragma unroll
  for (int off = 32; off; off >>= 1) ss += __shfl_down(ss, off);
  __shared__ float wred[4];
  const int lane = tid & 63, w = tid >> 6;
  if (lane == 0) wred[w] = ss;
  __syncthreads();
  if (tid == 0)
    invn[row] = 1.0f / fmaxf(sqrtf(wred[0] + wred[1] + wred[2] + wred[3]), 1e-12f);
}

__global__ __launch_bounds__(256) void tri_gemm_fly(const float* __restrict__ inF,
                                                    const float* __restrict__ invn,
                                                    float* __restrict__ accum) {
  enum { FBK = 64 };
  int t = blockIdx.x, bi = 0;
  while (t >= NB - bi) { t -= NB - bi; ++bi; }
  const int bj = bi + t;

  __shared__ __align__(16) ushort Asm[BT * FBK];
  __shared__ __align__(16) ushort Bsm[BT * FBK];

  const int tid  = threadIdx.x;
  const int lane = tid & 63;
  const int w    = tid >> 6;
  const int wr   = w >> 1, wc = w & 1;

  f32x4 acc[4][4] = {};
  const int rowA = bi * BT, rowB = bj * BT;

  for (int k0 = 0; k0 < DIM; k0 += FBK) {
    if (k0) __syncthreads();
    #pragma unroll
    for (int p = 0; p < 8; ++p) {
      int c   = p * 256 + tid;
      int isB = c >> 10;
      int cc  = c & 1023;
      int r   = cc >> 3;
      int s   = cc & 7;
      const int grow = (isB ? rowB : rowA) + r;
      const float4* src = (const float4*)(inF + (size_t)grow * DIM + k0 + s * 8);
      float4 v0 = src[0], v1 = src[1];
      int4 pack;
      ushort* h = (ushort*)&pack;
      h[0] = f32_to_bf16(v0.x); h[1] = f32_to_bf16(v0.y);
      h[2] = f32_to_bf16(v0.z); h[3] = f32_to_bf16(v0.w);
      h[4] = f32_to_bf16(v1.x); h[5] = f32_to_bf16(v1.y);
      h[6] = f32_to_bf16(v1.z); h[7] = f32_to_bf16(v1.w);
      *(int4*)((isB ? Bsm : Asm) + r * FBK + (s ^ (r & 7)) * 8) = pack;
    }
    __syncthreads();

    s16x8 af[2][4], bfv[2][4];
    const int fr = lane & 15, hi = lane >> 4;
    #pragma unroll
    for (int kk = 0; kk < 2; ++kk)
      #pragma unroll
      for (int m = 0; m < 4; ++m) {
        const int ra = wr * 64 + m * 16 + fr;
        af[kk][m] = *(const s16x8*)(Asm + ra * FBK + ((kk * 4 + hi) ^ (ra & 7)) * 8);
        const int rb = wc * 64 + m * 16 + fr;
        bfv[kk][m] = *(const s16x8*)(Bsm + rb * FBK + ((kk * 4 + hi) ^ (rb & 7)) * 8);
      }
    #pragma unroll
    for (int kk = 0; kk < 2; ++kk)
      #pragma unroll
      for (int m = 0; m < 4; ++m)
        #pragma unroll
        for (int n = 0; n < 4; ++n)
          acc[m][n] = __builtin_amdgcn_mfma_f32_16x16x32_bf16(af[kk][m], bfv[kk][n],
                                                              acc[m][n], 0, 0, 0);
  }

  float lsum = 0.f, lcnt = 0.f;
  const int gib = rowA + wr * 64;
  const int gjb = rowB + wc * 64;
  #pragma unroll
  for (int m = 0; m < 4; ++m)
    #pragma unroll
    for (int n = 0; n < 4; ++n)
      #pragma unroll
      for (int r = 0; r < 4; ++r) {
        int gi = gib + m * 16 + (lane >> 4) * 4 + r;
        int gj = gjb + n * 16 + (lane & 15);
        float s = acc[m][n][r] * invn[gi] * invn[gj];
        if (gi < gj && s > MARGIN) { lsum += s - MARGIN; lcnt += 1.f; }
      }
  #pragma unroll
  for (int off = 32; off; off >>= 1) {
    lsum += __shfl_down(lsum, off);
    lcnt += __shfl_down(lcnt, off);
  }
  __shared__ float rs[4], rc[4];
  if (lane == 0) { rs[w] = lsum; rc[w] = lcnt; }
  __syncthreads();
  if (tid == 0) {
    atomicAdd(&accum[0], rs[0] + rs[1] + rs[2] + rs[3]);
    atomicAdd(&accum[1], rc[0] + rc[1] + rc[2] + rc[3]);
  }
}

__global__ void finalize_kernel(const float* __restrict__ accum, float* __restrict__ out) {
  if (threadIdx.x == 0) out[0] = (accum[1] < 0.5f) ? 0.0f : accum[0] / accum[1];
}

extern "C" void kernel_launch(void* const* d_in, const int* in_sizes, int n_in,
                              void* d_out, int out_size, void* d_ws, size_t ws_size,
                              hipStream_t stream) {
  const float* in = (const float*)d_in[0];
  float* out = (float*)d_out;
  const size_t pn_bytes = (size_t)NROWS * ROWB;   // fp4: 4.2 MB (64 planes)

  if (ws_size >= pn_bytes + 2 * sizeof(float)) {
    unsigned char* pn = (unsigned char*)d_ws;
    float* accum = (float*)((char*)d_ws + pn_bytes);
    prep16<<<NROWS / 16, 1024, 0, stream>>>(in, pn, accum);
    tri_gemm<<<NBLK4, 64, 0, stream>>>(pn, accum);
    finalize_kernel<<<1, 64, 0, stream>>>(accum, out);
  } else {
    float* invn  = (float*)d_ws;
    float* accum = (float*)((char*)d_ws + NROWS * sizeof(float));
    prep_inv<<<NROWS, 256, 0, stream>>>(in, invn, accum);
    tri_gemm_fly<<<NBLK, 256, 0, stream>>>(in, invn, accum);
    finalize_kernel<<<1, 64, 0, stream>>>(accum, out);
  }
}

// Round 15
// 46.582 us; speedup vs baseline: 1.8424x; 1.7672x over previous
//
#include <hip/hip_runtime.h>
#include <stdint.h>

#define MARGIN 0.3f
#define NROWS 4096
#define DIM   2048
#define ROWB  1024                  // fp4: DIM/2 bytes per row
#define PLANE (NROWS * 16)          // 65536 B: one 16B-column plane
#define KSTEP (4 * PLANE)           // byte stride between K-steps (4 planes)
#define NKS   16
#define BT    128
#define NB    (NROWS / BT)          // 32
#define NBLK  (NB * (NB + 1) / 2)   // 528 (divisible by 8 -> clean XCD swizzle)

typedef float f32x4 __attribute__((ext_vector_type(4)));
typedef int   i32x4 __attribute__((ext_vector_type(4)));
typedef int   i32x8 __attribute__((ext_vector_type(8)));
typedef short s16x8 __attribute__((ext_vector_type(8)));

__device__ __forceinline__ ushort f32_to_bf16(float f) {
  uint32_t u = __float_as_uint(f);
  return (ushort)((u + 0x7FFFu + ((u >> 16) & 1u)) >> 16);
}

// e2m1 quantizer to grid {0,.5,1,1.5,2,3,4,6}, clamp at 6.
__device__ __forceinline__ unsigned f32_to_fp4(float y) {
  unsigned s = (__float_as_uint(y) >> 31) << 3;
  float a = fabsf(y);
  unsigned c;
  if      (a < 0.25f) c = 0;
  else if (a < 0.75f) c = 1;
  else if (a < 1.25f) c = 2;
  else if (a < 1.75f) c = 3;
  else if (a < 2.5f)  c = 4;
  else if (a < 3.5f)  c = 5;
  else if (a < 5.0f)  c = 6;
  else                c = 7;
  return s | c;
}

// ---------------------------------------------------------------------------
// prep16 (R12, verified fast): 16 rows per block, one wave per row. Lane l
// holds the 32 CONTIGUOUS elems of its row -> one 16B plane-chunk after
// quantization. Chunks transpose through a 16KB XOR-swizzled LDS buffer and
// stream out plane-major in 256B-contiguous runs (coalesced).
// Zeroes the accumulators.
// ---------------------------------------------------------------------------
__global__ __launch_bounds__(1024) void prep16(const float* __restrict__ in,
                                               unsigned char* __restrict__ pn,
                                               float* __restrict__ accum) {
  const int tid  = threadIdx.x;
  const int w    = tid >> 6;          // wave = row_local 0..15
  const int lane = tid & 63;
  const int row  = blockIdx.x * 16 + w;
  if (blockIdx.x == 0 && tid == 0) { accum[0] = 0.f; accum[1] = 0.f; }

  const float4* rp = (const float4*)(in + (size_t)row * DIM);
  float4 v[8];
  #pragma unroll
  for (int i = 0; i < 8; ++i) v[i] = rp[lane * 8 + i];   // 128B contiguous/lane

  float ss = 0.f;
  #pragma unroll
  for (int i = 0; i < 8; ++i)
    ss += v[i].x*v[i].x + v[i].y*v[i].y + v[i].z*v[i].z + v[i].w*v[i].w;
  #pragma unroll
  for (int off = 1; off < 64; off <<= 1) ss += __shfl_xor(ss, off);
  const float sc = 64.0f / fmaxf(sqrtf(ss), 1e-12f);     // norm * 2^6

  union { unsigned char bb[16]; int4 u; } q;
  #pragma unroll
  for (int i = 0; i < 8; ++i) {
    unsigned b0 = f32_to_fp4(v[i].x * sc) | (f32_to_fp4(v[i].y * sc) << 4);
    unsigned b1 = f32_to_fp4(v[i].z * sc) | (f32_to_fp4(v[i].w * sc) << 4);
    q.bb[2*i]   = (unsigned char)b0;
    q.bb[2*i+1] = (unsigned char)b1;
  }

  __shared__ int4 lt[1024];           // [row_local][chunk] with XOR swizzle
  lt[w * 64 + (lane ^ w)] = q.u;
  __syncthreads();

  const int p = tid >> 4, rl = tid & 15;
  int4 val = lt[rl * 64 + (p ^ rl)];
  *(int4*)(pn + (size_t)p * PLANE + ((size_t)blockIdx.x * 16 + rl) * 16) = val;
}

// ---------------------------------------------------------------------------
// tri_gemm (R11 structure, verbatim): one block per upper-tri 128x128 tile,
// 256 threads = 4 waves, each wave one 64x64 quadrant (4x4 frags).
// fp4 e2m1 via mfma_scale_f32_16x16x128_f8f6f4 (cbsz=blgp=4), scale 0x79 =
// 2^-6 -> acc = sim directly. No LDS, no barriers; fragments load straight
// from the plane-major fp4 matrix (16 lanes x 16B contiguous/quarter-wave).
// ROLLED K-loop (#pragma unroll 1) with named 2-deep buffers: R12-R14's
// fully-unrolled bodies (~20KB code) thrashed the 32KB I-cache -- 78us flat
// regardless of pipelining; R11's rolled loop ran ~28-33us.
// Intrinsic loads keep compiler-tracked vmcnt.
// ---------------------------------------------------------------------------
__device__ __forceinline__ void ld8(const unsigned char* __restrict__ p,
                                    uint32_t voA, uint32_t voB,
                                    i32x4 fa[4], i32x4 fb[4]) {
  #pragma unroll
  for (int m = 0; m < 4; ++m) {
    fa[m] = *(const i32x4*)(p + voA + m * 256);   // +16 rows per m
    fb[m] = *(const i32x4*)(p + voB + m * 256);
  }
}

__device__ __forceinline__ void mm16(const i32x4 fa[4], const i32x4 fb[4],
                                     f32x4 acc[4][4]) {
  const i32x4 z4 = {0, 0, 0, 0};
  #pragma unroll
  for (int m = 0; m < 4; ++m) {
    i32x8 am = __builtin_shufflevector(fa[m], z4, 0, 1, 2, 3, 4, 5, 6, 7);
    #pragma unroll
    for (int n = 0; n < 4; ++n) {
      i32x8 bn = __builtin_shufflevector(fb[n], z4, 0, 1, 2, 3, 4, 5, 6, 7);
      acc[m][n] = __builtin_amdgcn_mfma_scale_f32_16x16x128_f8f6f4(
          am, bn, acc[m][n],
          4, 4,                      // cbsz=fp4(e2m1), blgp=fp4(e2m1)
          0, 0x79797979,             // scale_a: e8m0 = 2^-6 everywhere
          0, 0x79797979);            // scale_b: e8m0 = 2^-6 everywhere
    }
  }
}

__global__ __launch_bounds__(256) void tri_gemm(const unsigned char* __restrict__ pn,
                                                float* __restrict__ accum) {
  // XCD-aware bijective swizzle (NBLK % 8 == 0)
  const int b = blockIdx.x;
  int t = (b & 7) * (NBLK / 8) + (b >> 3);
  int bi = 0;
  while (t >= NB - bi) { t -= NB - bi; ++bi; }
  const int bj = bi + t;

  const int tid  = threadIdx.x;
  const int lane = tid & 63;
  const int w    = tid >> 6;          // 0..3
  const int wr   = w >> 1;            // 0..1
  const int wc   = w & 1;             // 0..1
  const int fr   = lane & 15;         // fragment row within 16
  const int gq   = lane >> 4;         // 16B k-group within the 64B K-step

  f32x4 acc[4][4] = {};
  const int rowA = bi * BT, rowB = bj * BT;

  uint32_t voA = (uint32_t)gq * PLANE + (uint32_t)(rowA + wr * 64 + fr) * 16;
  uint32_t voB = (uint32_t)gq * PLANE + (uint32_t)(rowB + wc * 64 + fr) * 16;

  i32x4 fa0[4], fb0[4], fa1[4], fb1[4];

  // prologue: K-step 0
  ld8(pn, voA, voB, fa0, fb0);
  voA += KSTEP; voB += KSTEP;

  #pragma unroll 1
  for (int i = 0; i < 8; ++i) {
    // load step 2i+1 while computing step 2i
    ld8(pn, voA, voB, fa1, fb1);
    voA += KSTEP; voB += KSTEP;
    mm16(fa0, fb0, acc);
    // load step 2i+2 while computing step 2i+1 (skip past-the-end load)
    if (i != 7) {
      ld8(pn, voA, voB, fa0, fb0);
      voA += KSTEP; voB += KSTEP;
    }
    mm16(fa1, fb1, acc);
  }

  // ---- epilogue: mask + reduce (C/D layout is shape-determined) ----
  float lsum = 0.f, lcnt = 0.f;
  const int gib = rowA + wr * 64;
  const int gjb = rowB + wc * 64;
  #pragma unroll
  for (int m = 0; m < 4; ++m) {
    #pragma unroll
    for (int n = 0; n < 4; ++n) {
      #pragma unroll
      for (int r = 0; r < 4; ++r) {
        int gi = gib + m * 16 + gq * 4 + r;
        int gj = gjb + n * 16 + fr;
        float s = acc[m][n][r];
        if (gi < gj && s > MARGIN) { lsum += s - MARGIN; lcnt += 1.f; }
      }
    }
  }
  #pragma unroll
  for (int off = 32; off; off >>= 1) {
    lsum += __shfl_down(lsum, off);
    lcnt += __shfl_down(lcnt, off);
  }
  __shared__ float rs[4], rc[4];
  if (lane == 0) { rs[w] = lsum; rc[w] = lcnt; }
  __syncthreads();
  if (tid == 0) {
    atomicAdd(&accum[0], rs[0] + rs[1] + rs[2] + rs[3]);
    atomicAdd(&accum[1], rc[0] + rc[1] + rc[2] + rc[3]);
  }
}

// ---------------------------------------------------------------------------
// Fallback (tiny workspace): bf16 on-the-fly convert (verified R2 structure).
// ---------------------------------------------------------------------------
__global__ __launch_bounds__(256) void prep_inv(const float* __restrict__ in,
                                                float* __restrict__ invn,
                                                float* __restrict__ accum) {
  const int row = blockIdx.x;
  const int tid = threadIdx.x;
  if (row == 0 && tid == 0) { accum[0] = 0.f; accum[1] = 0.f; }
  const float4* rp = (const float4*)(in + (size_t)row * DIM);
  float4 v0 = rp[tid * 2];
  float4 v1 = rp[tid * 2 + 1];
  float ss = v0.x*v0.x + v0.y*v0.y + v0.z*v0.z + v0.w*v0.w
           + v1.x*v1.x + v1.y*v1.y + v1.z*v1.z + v1.w*v1.w;
  #pragma unroll
  for (int off = 32; off; off >>= 1) ss += __shfl_down(ss, off);
  __shared__ float wred[4];
  const int lane = tid & 63, w = tid >> 6;
  if (lane == 0) wred[w] = ss;
  __syncthreads();
  if (tid == 0)
    invn[row] = 1.0f / fmaxf(sqrtf(wred[0] + wred[1] + wred[2] + wred[3]), 1e-12f);
}

__global__ __launch_bounds__(256) void tri_gemm_fly(const float* __restrict__ inF,
                                                    const float* __restrict__ invn,
                                                    float* __restrict__ accum) {
  enum { FBK = 64 };
  int t = blockIdx.x, bi = 0;
  while (t >= NB - bi) { t -= NB - bi; ++bi; }
  const int bj = bi + t;

  __shared__ __align__(16) ushort Asm[BT * FBK];
  __shared__ __align__(16) ushort Bsm[BT * FBK];

  const int tid  = threadIdx.x;
  const int lane = tid & 63;
  const int w    = tid >> 6;
  const int wr   = w >> 1, wc = w & 1;

  f32x4 acc[4][4] = {};
  const int rowA = bi * BT, rowB = bj * BT;

  for (int k0 = 0; k0 < DIM; k0 += FBK) {
    if (k0) __syncthreads();
    #pragma unroll
    for (int p = 0; p < 8; ++p) {
      int c   = p * 256 + tid;
      int isB = c >> 10;
      int cc  = c & 1023;
      int r   = cc >> 3;
      int s   = cc & 7;
      const int grow = (isB ? rowB : rowA) + r;
      const float4* src = (const float4*)(inF + (size_t)grow * DIM + k0 + s * 8);
      float4 v0 = src[0], v1 = src[1];
      int4 pack;
      ushort* h = (ushort*)&pack;
      h[0] = f32_to_bf16(v0.x); h[1] = f32_to_bf16(v0.y);
      h[2] = f32_to_bf16(v0.z); h[3] = f32_to_bf16(v0.w);
      h[4] = f32_to_bf16(v1.x); h[5] = f32_to_bf16(v1.y);
      h[6] = f32_to_bf16(v1.z); h[7] = f32_to_bf16(v1.w);
      *(int4*)((isB ? Bsm : Asm) + r * FBK + (s ^ (r & 7)) * 8) = pack;
    }
    __syncthreads();

    s16x8 af[2][4], bfv[2][4];
    const int fr = lane & 15, hi = lane >> 4;
    #pragma unroll
    for (int kk = 0; kk < 2; ++kk)
      #pragma unroll
      for (int m = 0; m < 4; ++m) {
        const int ra = wr * 64 + m * 16 + fr;
        af[kk][m] = *(const s16x8*)(Asm + ra * FBK + ((kk * 4 + hi) ^ (ra & 7)) * 8);
        const int rb = wc * 64 + m * 16 + fr;
        bfv[kk][m] = *(const s16x8*)(Bsm + rb * FBK + ((kk * 4 + hi) ^ (rb & 7)) * 8);
      }
    #pragma unroll
    for (int kk = 0; kk < 2; ++kk)
      #pragma unroll
      for (int m = 0; m < 4; ++m)
        #pragma unroll
        for (int n = 0; n < 4; ++n)
          acc[m][n] = __builtin_amdgcn_mfma_f32_16x16x32_bf16(af[kk][m], bfv[kk][n],
                                                              acc[m][n], 0, 0, 0);
  }

  float lsum = 0.f, lcnt = 0.f;
  const int gib = rowA + wr * 64;
  const int gjb = rowB + wc * 64;
  #pragma unroll
  for (int m = 0; m < 4; ++m)
    #pragma unroll
    for (int n = 0; n < 4; ++n)
      #pragma unroll
      for (int r = 0; r < 4; ++r) {
        int gi = gib + m * 16 + (lane >> 4) * 4 + r;
        int gj = gjb + n * 16 + (lane & 15);
        float s = acc[m][n][r] * invn[gi] * invn[gj];
        if (gi < gj && s > MARGIN) { lsum += s - MARGIN; lcnt += 1.f; }
      }
  #pragma unroll
  for (int off = 32; off; off >>= 1) {
    lsum += __shfl_down(lsum, off);
    lcnt += __shfl_down(lcnt, off);
  }
  __shared__ float rs[4], rc[4];
  if (lane == 0) { rs[w] = lsum; rc[w] = lcnt; }
  __syncthreads();
  if (tid == 0) {
    atomicAdd(&accum[0], rs[0] + rs[1] + rs[2] + rs[3]);
    atomicAdd(&accum[1], rc[0] + rc[1] + rc[2] + rc[3]);
  }
}

__global__ void finalize_kernel(const float* __restrict__ accum, float* __restrict__ out) {
  if (threadIdx.x == 0) out[0] = (accum[1] < 0.5f) ? 0.0f : accum[0] / accum[1];
}

extern "C" void kernel_launch(void* const* d_in, const int* in_sizes, int n_in,
                              void* d_out, int out_size, void* d_ws, size_t ws_size,
                              hipStream_t stream) {
  const float* in = (const float*)d_in[0];
  float* out = (float*)d_out;
  const size_t pn_bytes = (size_t)NROWS * ROWB;   // fp4: 4.2 MB (64 planes)

  if (ws_size >= pn_bytes + 2 * sizeof(float)) {
    unsigned char* pn = (unsigned char*)d_ws;
    float* accum = (float*)((char*)d_ws + pn_bytes);
    prep16<<<NROWS / 16, 1024, 0, stream>>>(in, pn, accum);
    tri_gemm<<<NBLK, 256, 0, stream>>>(pn, accum);
    finalize_kernel<<<1, 64, 0, stream>>>(accum, out);
  } else {
    float* invn  = (float*)d_ws;
    float* accum = (float*)((char*)d_ws + NROWS * sizeof(float));
    prep_inv<<<NROWS, 256, 0, stream>>>(in, invn, accum);
    tri_gemm_fly<<<NBLK, 256, 0, stream>>>(in, invn, accum);
    finalize_kernel<<<1, 64, 0, stream>>>(accum, out);
  }
}